// Round 1
// baseline (90.371 us; speedup 1.0000x reference)
//
#include <hip/hip_runtime.h>
#include <math.h>

constexpr int BLOCKS  = 1024;
constexpr int THREADS = 256;
constexpr int WAVES   = THREADS / 64;

// Stage 1: grid-stride float4 loads, per-thread dual accumulation,
// wave shuffle reduce + LDS cross-wave reduce, 2 floats per block to d_ws.
__global__ __launch_bounds__(THREADS)
void rul_partial(const float* __restrict__ pred,
                 const float* __restrict__ lab,
                 float* __restrict__ partials, int n) {
    const float4* p4 = reinterpret_cast<const float4*>(pred);
    const float4* l4 = reinterpret_cast<const float4*>(lab);
    const int n4 = n >> 2;  // N is divisible by 4

    const float cneg = -1.0f / 13.0f;
    const float cpos =  1.0f / 10.0f;

    float sc = 0.0f;  // sum of exp-term - 1
    float sq = 0.0f;  // sum of d*d

    for (int i = blockIdx.x * THREADS + threadIdx.x; i < n4;
         i += gridDim.x * THREADS) {
        float4 p = p4[i];
        float4 l = l4[i];
        float d0 = p.x - l.x;
        float d1 = p.y - l.y;
        float d2 = p.z - l.z;
        float d3 = p.w - l.w;

        float t0 = d0 * (d0 < 0.0f ? cneg : cpos);
        float t1 = d1 * (d1 < 0.0f ? cneg : cpos);
        float t2 = d2 * (d2 < 0.0f ? cneg : cpos);
        float t3 = d3 * (d3 < 0.0f ? cneg : cpos);

        sc += (__expf(t0) - 1.0f) + (__expf(t1) - 1.0f)
            + (__expf(t2) - 1.0f) + (__expf(t3) - 1.0f);
        sq += d0 * d0 + d1 * d1 + d2 * d2 + d3 * d3;
    }

    // wave-64 butterfly-ish down-shuffle reduction
    #pragma unroll
    for (int off = 32; off > 0; off >>= 1) {
        sc += __shfl_down(sc, off, 64);
        sq += __shfl_down(sq, off, 64);
    }

    __shared__ float s_sc[WAVES];
    __shared__ float s_sq[WAVES];
    const int lane = threadIdx.x & 63;
    const int wave = threadIdx.x >> 6;
    if (lane == 0) { s_sc[wave] = sc; s_sq[wave] = sq; }
    __syncthreads();

    if (threadIdx.x == 0) {
        float tsc = 0.0f, tsq = 0.0f;
        #pragma unroll
        for (int w = 0; w < WAVES; ++w) { tsc += s_sc[w]; tsq += s_sq[w]; }
        partials[blockIdx.x]          = tsc;
        partials[BLOCKS + blockIdx.x] = tsq;
    }
}

// Stage 2: one block folds 1024 partial pairs and writes the scalar.
__global__ __launch_bounds__(THREADS)
void rul_final(const float* __restrict__ partials,
               float* __restrict__ out, int n) {
    float sc = 0.0f, sq = 0.0f;
    for (int i = threadIdx.x; i < BLOCKS; i += THREADS) {
        sc += partials[i];
        sq += partials[BLOCKS + i];
    }

    #pragma unroll
    for (int off = 32; off > 0; off >>= 1) {
        sc += __shfl_down(sc, off, 64);
        sq += __shfl_down(sq, off, 64);
    }

    __shared__ float s_sc[WAVES];
    __shared__ float s_sq[WAVES];
    const int lane = threadIdx.x & 63;
    const int wave = threadIdx.x >> 6;
    if (lane == 0) { s_sc[wave] = sc; s_sq[wave] = sq; }
    __syncthreads();

    if (threadIdx.x == 0) {
        float tsc = 0.0f, tsq = 0.0f;
        #pragma unroll
        for (int w = 0; w < WAVES; ++w) { tsc += s_sc[w]; tsq += s_sq[w]; }
        float rmse = sqrtf(tsq / (float)n);
        out[0] = 0.5f * tsc + 0.5f * rmse;
    }
}

extern "C" void kernel_launch(void* const* d_in, const int* in_sizes, int n_in,
                              void* d_out, int out_size, void* d_ws, size_t ws_size,
                              hipStream_t stream) {
    const float* pred = (const float*)d_in[0];
    const float* lab  = (const float*)d_in[1];
    const int n = in_sizes[0];

    float* partials = (float*)d_ws;  // 2 * BLOCKS floats, fully overwritten

    rul_partial<<<BLOCKS, THREADS, 0, stream>>>(pred, lab, partials, n);
    rul_final<<<1, THREADS, 0, stream>>>(partials, (float*)d_out, n);
}